// Round 12
// baseline (1107.537 us; speedup 1.0000x reference)
//
#include <hip/hip_runtime.h>
#include <cstdint>

#define DDIM 128
#define MLAT 4096
#define KSEL 64

typedef __bf16  bf16x8  __attribute__((ext_vector_type(8)));
typedef float   f32x4   __attribute__((ext_vector_type(4)));
typedef ushort  ushort8 __attribute__((ext_vector_type(8)));
typedef unsigned uint32x4 __attribute__((ext_vector_type(4)));

__device__ __forceinline__ ushort bf16rn(float v) {
    unsigned b = __float_as_uint(v);
    return (ushort)((b + 0x7FFFu + ((b >> 16) & 1u)) >> 16);
}

// ---------------------------------------------------------------------------
// K0 (prep): W_enc-split (MFMA-packed) | W_dec transpose. (validated R9-R11)
__global__ __launch_bounds__(256) void k_prep(
        const float* __restrict__ Wenc,
        ushort* __restrict__ whiP, ushort* __restrict__ wloP,
        const float* __restrict__ Wdec, float* __restrict__ WdT) {
    int b = blockIdx.x;
    if (b < 512) {
        int e = (b * 256 + threadIdx.x) * 4;
        float4 v = *(const float4*)(Wenc + e);
        float a[4] = {v.x, v.y, v.z, v.w};
        int c = e >> 7, k0 = e & 127;
        int ks = k0 >> 5, lq = (k0 >> 3) & 3, j0 = k0 & 7;
        int out = (((c >> 4) * 4 + ks) * 4 + lq) * 128 + (c & 15) * 8 + j0;
        ushort4 h, l;
        ushort* hp = (ushort*)&h; ushort* lp = (ushort*)&l;
#pragma unroll
        for (int i = 0; i < 4; ++i) {
            unsigned ua = __float_as_uint(a[i]);
            unsigned rh = (ua + 0x7FFFu + ((ua >> 16) & 1u)) & 0xFFFF0000u;
            float lo = a[i] - __uint_as_float(rh);
            hp[i] = (ushort)(rh >> 16);
            lp[i] = bf16rn(lo);
        }
        *(ushort4*)(whiP + out) = h;
        *(ushort4*)(wloP + out) = l;
    } else {
        int tid = (b - 512) * 256 + threadIdx.x;    // coalesced read of Wdec
        int d = tid >> 12, j = tid & 4095;
        WdT[j * DDIM + d] = Wdec[tid];
    }
}

// ---------------------------------------------------------------------------
// K1: z~ = relu((x-b_dec) @ W_enc^T + b_enc), split-bf16 MFMA, f32 store.
// CHANGE vs R11: operand-SWAPPED mfma (w_frag as A, x_frag as B) computes the
// transposed tile: lane holds 4 CONSECUTIVE COLS of one z~ row -> float4
// epilogue stores (4x fewer store instrs). Products occupy identical k-tree
// leaves, chain order (hh,hl,lh) unchanged -> z~ BIT-IDENTICAL to R3-R11.
__global__ __launch_bounds__(256, 2) void k_encode_mfma(
        const float* __restrict__ x, const float* __restrict__ bdec,
        const ushort* __restrict__ whiP, const ushort* __restrict__ wloP,
        const float* __restrict__ benc, float* __restrict__ zout) {
    __shared__ __attribute__((aligned(16))) ushort Ah[128 * 128];
    __shared__ __attribute__((aligned(16))) ushort Al[128 * 128];

    const int t    = threadIdx.x;
    const int lane = t & 63;
    const int w    = t >> 6;
    const int i0   = blockIdx.x << 7;

    {   // stage A: read x f32, subtract b_dec, split hi/lo, swizzled LDS store
        int row = t >> 1, half = t & 1;
        const float* xr = x + (size_t)(i0 + row) * DDIM + half * 64;
        const float* bd = bdec + half * 64;
        int base = row * 256 + half * 128;
        int swz  = (row & 7) << 4;
#pragma unroll
        for (int j = 0; j < 8; ++j) {
            float4 v0 = *(const float4*)(xr + j * 8);
            float4 v1 = *(const float4*)(xr + j * 8 + 4);
            float4 b0 = *(const float4*)(bd + j * 8);
            float4 b1 = *(const float4*)(bd + j * 8 + 4);
            float a[8] = {v0.x - b0.x, v0.y - b0.y, v0.z - b0.z, v0.w - b0.w,
                          v1.x - b1.x, v1.y - b1.y, v1.z - b1.z, v1.w - b1.w};
            ushort8 h8, l8;
#pragma unroll
            for (int i = 0; i < 8; ++i) {
                unsigned ua = __float_as_uint(a[i]);
                unsigned rh = (ua + 0x7FFFu + ((ua >> 16) & 1u)) & 0xFFFF0000u;
                float lo = a[i] - __uint_as_float(rh);
                h8[i] = (ushort)(rh >> 16);
                l8[i] = bf16rn(lo);
            }
            int off = (base + j * 16) ^ swz;
            *(ushort8*)((char*)Ah + off) = h8;
            *(ushort8*)((char*)Al + off) = l8;
        }
    }
    __syncthreads();

    const int lr = lane & 15;
    const int lq = lane >> 4;

    for (int cp = 0; cp < 16; ++cp) {
        const int jb = cp * 256 + (w << 6);
        const int tb = jb >> 4;
        f32x4 acc[8][4];
#pragma unroll
        for (int rf = 0; rf < 8; ++rf)
#pragma unroll
            for (int cf = 0; cf < 4; ++cf) acc[rf][cf] = (f32x4){0.f, 0.f, 0.f, 0.f};

#define BOFF(cf, ks) ((size_t)((((tb + (cf)) << 2) + (ks)) << 9) + (lane << 3))
        bf16x8 bhc[4], blc[4];
#pragma unroll
        for (int cf = 0; cf < 4; ++cf) {
            bhc[cf] = *(const bf16x8*)(whiP + BOFF(cf, 0));
            blc[cf] = *(const bf16x8*)(wloP + BOFF(cf, 0));
        }
#pragma unroll
        for (int ks = 0; ks < 4; ++ks) {
            bf16x8 bhn[4], bln[4];
            if (ks < 3) {
#pragma unroll
                for (int cf = 0; cf < 4; ++cf) {
                    bhn[cf] = *(const bf16x8*)(whiP + BOFF(cf, ks + 1));
                    bln[cf] = *(const bf16x8*)(wloP + BOFF(cf, ks + 1));
                }
            }
#pragma unroll
            for (int rf = 0; rf < 8; ++rf) {
                int row = rf * 16 + lr;
                int off = (row * 256 + ks * 64 + lq * 16) ^ ((row & 7) << 4);
                bf16x8 ah = *(const bf16x8*)((const char*)Ah + off);
                bf16x8 al = *(const bf16x8*)((const char*)Al + off);
                // operand-swapped: D' = W-tile x x-tile (transposed output).
                // chain order per output unchanged: hh, hl, lh
#pragma unroll
                for (int cf = 0; cf < 4; ++cf) {
                    acc[rf][cf] = __builtin_amdgcn_mfma_f32_16x16x32_bf16(bhc[cf], ah, acc[rf][cf], 0, 0, 0);
                    acc[rf][cf] = __builtin_amdgcn_mfma_f32_16x16x32_bf16(blc[cf], ah, acc[rf][cf], 0, 0, 0);
                    acc[rf][cf] = __builtin_amdgcn_mfma_f32_16x16x32_bf16(bhc[cf], al, acc[rf][cf], 0, 0, 0);
                }
            }
            if (ks < 3) {
#pragma unroll
                for (int cf = 0; cf < 4; ++cf) { bhc[cf] = bhn[cf]; blc[cf] = bln[cf]; }
            }
        }
#undef BOFF
        // epilogue (transposed tile): lane owns row = i0+rf*16+lr,
        // cols = jb+cf*16+lq*4 .. +3  -> float4 stores
#pragma unroll
        for (int rf = 0; rf < 8; ++rf) {
            size_t rowbase = (size_t)(i0 + rf * 16 + lr) * MLAT;
#pragma unroll
            for (int cf = 0; cf < 4; ++cf) {
                int col = jb + cf * 16 + (lq << 2);
                float4 be = *(const float4*)(benc + col);
                f32x4 v = acc[rf][cf];
                float4 o = {fmaxf(v[0] + be.x, 0.f), fmaxf(v[1] + be.y, 0.f),
                            fmaxf(v[2] + be.z, 0.f), fmaxf(v[3] + be.w, 0.f)};
                *(float4*)(&zout[rowbase + col]) = o;
            }
        }
    }
}

// ---------------------------------------------------------------------------
// K2: R11 VERBATIM (validated selection; cached accesses; parity barriers).
__global__ __launch_bounds__(128, 8) void k_topk_decode(
        float* __restrict__ zbuf, float* __restrict__ xhat,
        const float* __restrict__ WdT, const float* __restrict__ bdec,
        const float* __restrict__ x, const float* __restrict__ Wenc,
        const float* __restrict__ benc) {
    __shared__ float sval[KSEL];
    __shared__ int   sidx[KSEL];
    __shared__ float bval[128];
    __shared__ int   bidx[128];
    __shared__ unsigned char bselm[128];
    __shared__ unsigned scom[6];
    __shared__ int stot[2];

    const int tid  = threadIdx.x;     // 0..127
    const int lane = tid & 63;
    const int w    = tid >> 6;        // wave 0/1: owns elements w*2048 ..
    const size_t row = blockIdx.x;
    float* zr = zbuf + row * MLAT;
    const uint32x4* zu = (const uint32x4*)zr + (w << 9);

    // element (half-local): q*256 + lane*4 + c ; global = w*2048 + that
    uint32x4 u[8];
#pragma unroll
    for (int q = 0; q < 8; ++q) u[q] = zu[(q << 6) + lane];

    // ---- row max (v >= 0 so uint order == float order)
    unsigned mx = 0u;
#pragma unroll
    for (int q = 0; q < 8; ++q)
        mx = max(mx, max(max(u[q][0], u[q][1]), max(u[q][2], u[q][3])));
#pragma unroll
    for (int d = 32; d >= 1; d >>= 1) mx = max(mx, (unsigned)__shfl_xor((int)mx, d, 64));
    if (lane == 0) scom[w] = mx;
    __syncthreads();
    mx = max(scom[0], scom[1]);

    // ---- distributed count(v >= T): parity-buffered, 1 barrier per call
    unsigned par = 0;
#define CNT_GE(T, OUTC)                                              \
    {                                                                \
        int _c = 0;                                                  \
        _Pragma("unroll")                                            \
        for (int q = 0; q < 8; ++q) {                                \
            _c += __popcll(__ballot(u[q][0] >= (T)));                \
            _c += __popcll(__ballot(u[q][1] >= (T)));                \
            _c += __popcll(__ballot(u[q][2] >= (T)));                \
            _c += __popcll(__ballot(u[q][3] >= (T)));                \
        }                                                            \
        if (lane == 0) scom[2 + 2 * par + w] = (unsigned)_c;         \
        __syncthreads();                                             \
        OUTC = (int)(scom[2 + 2 * par] + scom[3 + 2 * par]);         \
        par ^= 1u;                                                   \
    }

    // ---- bisection for T (seed window, early exit) -- decisions == R6-R11
    unsigned T;
    {
        unsigned hi = mx + 1u;
        unsigned lo = (mx > 0x01800000u) ? (mx - 0x01800000u) : 0u;
        int c;
        CNT_GE(lo, c);
        if (c < KSEL) { lo = 0u; c = MLAT; }
        if (c == KSEL) {
            T = lo;
        } else {
            for (;;) {
                if (hi - lo <= 1u) { T = lo; break; }
                unsigned mid = lo + ((hi - lo) >> 1);
                int cm;
                CNT_GE(mid, cm);
                if (cm == KSEL) { T = mid; break; }
                if (cm > KSEL) lo = mid; else hi = mid;
            }
        }
    }

    // ---- band classification (identical constants to R5-R11)
    const float tau   = __uint_as_float(T);
    const float DELTA = 2.5e-4f;
    const float PAD   = 5.0e-5f;
    const unsigned DH = __float_as_uint(tau + DELTA + PAD);
    const unsigned DL = __float_as_uint(fmaxf(tau - DELTA, 0.f));

    unsigned inm = 0u, bandm = 0u;   // per-lane 32-bit masks, bit = q*4+c
#pragma unroll
    for (int q = 0; q < 8; ++q) {
#pragma unroll
        for (int c = 0; c < 4; ++c) {
            unsigned bit = 1u << (4 * q + c);
            if (u[q][c] > DH) inm |= bit;
            else if (u[q][c] >= DL) bandm |= bit;
        }
    }
    {
        int packed = (__popc(inm) << 16) | __popc(bandm);
#pragma unroll
        for (int d = 32; d >= 1; d >>= 1) packed += __shfl_xor(packed, d, 64);
        if (lane == 0) scom[2 + 2 * par + w] = (unsigned)packed;
        __syncthreads();
    }
    int A   = (int)((scom[2 + 2 * par] >> 16) + (scom[3 + 2 * par] >> 16));
    int BCt = (int)((scom[2 + 2 * par] & 0xFFFFu) + (scom[3 + 2 * par] & 0xFFFFu));
    int need = KSEL - A;

    unsigned sel;
    if (need <= 0) {
        sel = inm;
    } else if (BCt == need) {
        sel = inm | bandm;
    } else {
        // ---- exact fixup: recompute band members with np-order f32 chain
        int BC2 = min(BCt, 128);
        int bc = __popc(bandm);
        int pre = bc;
#pragma unroll
        for (int d = 1; d < 64; d <<= 1) {
            int y = __shfl_up(pre, d, 64);
            if (lane >= d) pre += y;
        }
        int wtot = __shfl(pre, 63, 64);
        if (lane == 0) stot[w] = wtot;
        __syncthreads();
        int sbase = (pre - bc) + (w ? stot[0] : 0);
        {
            unsigned mm = bandm; int o = 0;
            while (mm) {
                int bp = __ffs(mm) - 1; mm &= mm - 1;
                int slot = sbase + o; ++o;
                if (slot < 128)
                    bidx[slot] = (w << 11) + ((bp >> 2) << 8) + (lane << 2) + (bp & 3);
            }
        }
        __syncthreads();
        for (int s = tid; s < BC2; s += 128) {
            int j = bidx[s];
            const float* wr = Wenc + (size_t)j * DDIM;
            const float* xr = x + row * DDIM;
            float a = 0.f;
            for (int k = 0; k < DDIM; ++k) a = fmaf(xr[k] - bdec[k], wr[k], a);
            bval[s] = fmaxf(a + benc[j], 0.f);
        }
        __syncthreads();
        if (tid == 0) {
            for (int s = 0; s < BC2; ++s) bselm[s] = 0;
            int take = min(need, BC2);
            for (int it = 0; it < take; ++it) {
                float bv = -1.f; int bi = 0x7FFFFFFF, bs = 0;
                for (int s = 0; s < BC2; ++s) {
                    if (bselm[s]) continue;
                    float v = bval[s]; int j = bidx[s];
                    if (v > bv || (v == bv && j < bi)) { bv = v; bi = j; bs = s; }
                }
                bselm[bs] = 1;
            }
        }
        __syncthreads();
        sel = inm;
        {
            unsigned mm = bandm; int o = 0;
            while (mm) {
                int bp = __ffs(mm) - 1; mm &= mm - 1;
                int slot = sbase + o; ++o;
                if (slot < 128 && bselm[slot]) sel |= 1u << bp;
            }
        }
        __syncthreads();
    }

    // ---- compaction position across both waves
    int scnt = __popc(sel);
    int pre = scnt;
#pragma unroll
    for (int d = 1; d < 64; d <<= 1) {
        int y = __shfl_up(pre, d, 64);
        if (lane >= d) pre += y;
    }
    int wtot2 = __shfl(pre, 63, 64);
    if (lane == 0) stot[w] = wtot2;
    __syncthreads();
    int pos = pre - scnt + (w ? stot[0] : 0);
    int total = stot[0] + stot[1];

    // ---- finalize z (own half) + compact (v, idx) to LDS
    uint32x4* zw = (uint32x4*)zr + (w << 9);
#pragma unroll
    for (int q = 0; q < 8; ++q) {
        uint32x4 o;
        bool s0 = (sel >> (4 * q + 0)) & 1u;
        bool s1 = (sel >> (4 * q + 1)) & 1u;
        bool s2 = (sel >> (4 * q + 2)) & 1u;
        bool s3 = (sel >> (4 * q + 3)) & 1u;
        o[0] = s0 ? u[q][0] : 0u;
        o[1] = s1 ? u[q][1] : 0u;
        o[2] = s2 ? u[q][2] : 0u;
        o[3] = s3 ? u[q][3] : 0u;
        int base = (w << 11) + (q << 8) + (lane << 2);
        if (s0 && pos < KSEL) { sval[pos] = __uint_as_float(u[q][0]); sidx[pos] = base + 0; ++pos; }
        if (s1 && pos < KSEL) { sval[pos] = __uint_as_float(u[q][1]); sidx[pos] = base + 1; ++pos; }
        if (s2 && pos < KSEL) { sval[pos] = __uint_as_float(u[q][2]); sidx[pos] = base + 2; ++pos; }
        if (s3 && pos < KSEL) { sval[pos] = __uint_as_float(u[q][3]); sidx[pos] = base + 3; ++pos; }
        zw[(q << 6) + lane] = o;
    }
    __syncthreads();

    // ---- decode: thread tid owns output dim d = tid (WdT stays L2-cached)
    float a = bdec[tid];
    int tt = min(total, KSEL);
#pragma unroll 4
    for (int s = 0; s < tt; ++s) {
        float v = sval[s];
        int   j = sidx[s];
        a = fmaf(v, WdT[(size_t)j * DDIM + tid], a);
    }
    xhat[row * DDIM + tid] = a;
}

// ---------------------------------------------------------------------------
extern "C" void kernel_launch(void* const* d_in, const int* in_sizes, int n_in,
                              void* d_out, int out_size, void* d_ws, size_t ws_size,
                              hipStream_t stream) {
    const float* x    = (const float*)d_in[0];
    const float* Wenc = (const float*)d_in[1];
    const float* benc = (const float*)d_in[2];
    const float* Wdec = (const float*)d_in[3];
    const float* bdec = (const float*)d_in[4];

    const int N = in_sizes[0] / DDIM;               // 65536
    float* xhat = (float*)d_out;                    // [N][128] f32 (final)
    float* zbuf = (float*)d_out + (size_t)N * DDIM; // [N][4096] (z~, finalized in place)

    // workspace: whiP | wloP | WdT  (1 MB + 1 MB + 2 MB)
    ushort* whiP = (ushort*)d_ws;
    ushort* wloP = whiP + (size_t)MLAT * DDIM;
    float*  WdT  = (float*)((char*)d_ws + 2u * 1024u * 1024u);

    k_prep<<<dim3(512 + 2048), dim3(256), 0, stream>>>(Wenc, whiP, wloP, Wdec, WdT);
    k_encode_mfma<<<dim3(N / 128), dim3(256), 0, stream>>>(x, bdec, whiP, wloP, benc, zbuf);
    k_topk_decode<<<dim3(N), dim3(128), 0, stream>>>(zbuf, xhat, WdT, bdec, x, Wenc, benc);
}

// Round 13
// 841.013 us; speedup vs baseline: 1.3169x; 1.3169x over previous
//
#include <hip/hip_runtime.h>
#include <cstdint>

#define DDIM 128
#define MLAT 4096
#define KSEL 64

typedef __bf16  bf16x8  __attribute__((ext_vector_type(8)));
typedef float   f32x4   __attribute__((ext_vector_type(4)));

__device__ __forceinline__ ushort bf16rn(float v) {
    unsigned b = __float_as_uint(v);
    return (ushort)((b + 0x7FFFu + ((b >> 16) & 1u)) >> 16);
}

// ---------------------------------------------------------------------------
// K0a: split (x - b_dec) into bf16 hi/lo pair arrays (RN-even), 4 elems/thread
__global__ __launch_bounds__(256) void k_split_x(const float* __restrict__ x,
                                                 const float* __restrict__ bdec,
                                                 ushort* __restrict__ xhi,
                                                 ushort* __restrict__ xlo) {
    int e = (blockIdx.x * 256 + threadIdx.x) * 4;
    float4 v = *(const float4*)(x + e);
    float4 bd = *(const float4*)(bdec + (e & 127));
    float a[4] = {v.x - bd.x, v.y - bd.y, v.z - bd.z, v.w - bd.w};
    ushort4 h, l;
    ushort* hp = (ushort*)&h; ushort* lp = (ushort*)&l;
#pragma unroll
    for (int i = 0; i < 4; ++i) {
        unsigned ua = __float_as_uint(a[i]);
        unsigned rh = (ua + 0x7FFFu + ((ua >> 16) & 1u)) & 0xFFFF0000u;
        float lo = a[i] - __uint_as_float(rh);
        hp[i] = (ushort)(rh >> 16);
        lp[i] = bf16rn(lo);
    }
    *(ushort4*)(xhi + e) = h;
    *(ushort4*)(xlo + e) = l;
}

// ---------------------------------------------------------------------------
// K0b (prep): W_enc-split (MFMA-packed) | W_dec transpose.
__global__ __launch_bounds__(256) void k_prep(
        const float* __restrict__ Wenc,
        ushort* __restrict__ whiP, ushort* __restrict__ wloP,
        const float* __restrict__ Wdec, float* __restrict__ WdT) {
    int b = blockIdx.x;
    if (b < 512) {
        int e = (b * 256 + threadIdx.x) * 4;
        float4 v = *(const float4*)(Wenc + e);
        float a[4] = {v.x, v.y, v.z, v.w};
        int c = e >> 7, k0 = e & 127;
        int ks = k0 >> 5, lq = (k0 >> 3) & 3, j0 = k0 & 7;
        int out = (((c >> 4) * 4 + ks) * 4 + lq) * 128 + (c & 15) * 8 + j0;
        ushort4 h, l;
        ushort* hp = (ushort*)&h; ushort* lp = (ushort*)&l;
#pragma unroll
        for (int i = 0; i < 4; ++i) {
            unsigned ua = __float_as_uint(a[i]);
            unsigned rh = (ua + 0x7FFFu + ((ua >> 16) & 1u)) & 0xFFFF0000u;
            float lo = a[i] - __uint_as_float(rh);
            hp[i] = (ushort)(rh >> 16);
            lp[i] = bf16rn(lo);
        }
        *(ushort4*)(whiP + out) = h;
        *(ushort4*)(wloP + out) = l;
    } else {
        int tid = (b - 512) * 256 + threadIdx.x;    // coalesced read of Wdec
        int d = tid >> 12, j = tid & 4095;
        WdT[j * DDIM + d] = Wdec[tid];
    }
}

// ---------------------------------------------------------------------------
// K1: z~ = relu((x-b_dec) @ W_enc^T + b_enc), split-bf16 MFMA, f32 store.
// R9 VERBATIM: canonical operand order, scalar-store epilogue (4 rows/instr
// write pattern -- R12's transposed float4 epilogue regressed 240 us).
__global__ __launch_bounds__(256, 2) void k_encode_mfma(
        const ushort* __restrict__ xhi, const ushort* __restrict__ xlo,
        const ushort* __restrict__ whiP, const ushort* __restrict__ wloP,
        const float* __restrict__ benc, float* __restrict__ zout) {
    __shared__ __attribute__((aligned(16))) ushort Ah[128 * 128];
    __shared__ __attribute__((aligned(16))) ushort Al[128 * 128];

    const int t    = threadIdx.x;
    const int lane = t & 63;
    const int w    = t >> 6;
    const int i0   = blockIdx.x << 7;

    {   // stage A splits, swizzled: byte = row*256 + k*2, ^ ((row&7)<<4)
        int row = t >> 1, half = t & 1;
        const ushort* sh = xhi + (size_t)(i0 + row) * DDIM + half * 64;
        const ushort* sl = xlo + (size_t)(i0 + row) * DDIM + half * 64;
        int base = row * 256 + half * 128;
        int swz  = (row & 7) << 4;
#pragma unroll
        for (int j = 0; j < 8; ++j) {
            int off = (base + j * 16) ^ swz;
            *(bf16x8*)((char*)Ah + off) = *(const bf16x8*)(sh + j * 8);
            *(bf16x8*)((char*)Al + off) = *(const bf16x8*)(sl + j * 8);
        }
    }
    __syncthreads();

    const int lr = lane & 15;
    const int lq = lane >> 4;

    for (int cp = 0; cp < 16; ++cp) {
        const int jb = cp * 256 + (w << 6);
        const int tb = jb >> 4;
        f32x4 acc[8][4];
#pragma unroll
        for (int rf = 0; rf < 8; ++rf)
#pragma unroll
            for (int cf = 0; cf < 4; ++cf) acc[rf][cf] = (f32x4){0.f, 0.f, 0.f, 0.f};

#define BOFF(cf, ks) ((size_t)((((tb + (cf)) << 2) + (ks)) << 9) + (lane << 3))
        bf16x8 bhc[4], blc[4];
#pragma unroll
        for (int cf = 0; cf < 4; ++cf) {
            bhc[cf] = *(const bf16x8*)(whiP + BOFF(cf, 0));
            blc[cf] = *(const bf16x8*)(wloP + BOFF(cf, 0));
        }
#pragma unroll
        for (int ks = 0; ks < 4; ++ks) {
            bf16x8 bhn[4], bln[4];
            if (ks < 3) {
#pragma unroll
                for (int cf = 0; cf < 4; ++cf) {
                    bhn[cf] = *(const bf16x8*)(whiP + BOFF(cf, ks + 1));
                    bln[cf] = *(const bf16x8*)(wloP + BOFF(cf, ks + 1));
                }
            }
#pragma unroll
            for (int rf = 0; rf < 8; ++rf) {
                int row = rf * 16 + lr;
                int off = (row * 256 + ks * 64 + lq * 16) ^ ((row & 7) << 4);
                bf16x8 ah = *(const bf16x8*)((const char*)Ah + off);
                bf16x8 al = *(const bf16x8*)((const char*)Al + off);
#pragma unroll
                for (int cf = 0; cf < 4; ++cf) {
                    acc[rf][cf] = __builtin_amdgcn_mfma_f32_16x16x32_bf16(ah, bhc[cf], acc[rf][cf], 0, 0, 0);
                    acc[rf][cf] = __builtin_amdgcn_mfma_f32_16x16x32_bf16(ah, blc[cf], acc[rf][cf], 0, 0, 0);
                    acc[rf][cf] = __builtin_amdgcn_mfma_f32_16x16x32_bf16(al, bhc[cf], acc[rf][cf], 0, 0, 0);
                }
            }
            if (ks < 3) {
#pragma unroll
                for (int cf = 0; cf < 4; ++cf) { bhc[cf] = bhn[cf]; blc[cf] = bln[cf]; }
            }
        }
#undef BOFF
        // epilogue: + b_enc, relu, cached scalar f32 stores
#pragma unroll
        for (int rf = 0; rf < 8; ++rf)
#pragma unroll
            for (int cf = 0; cf < 4; ++cf) {
                int col = jb + cf * 16 + lr;
                float be = benc[col];
#pragma unroll
                for (int r = 0; r < 4; ++r) {
                    int row = i0 + rf * 16 + lq * 4 + r;
                    zout[(size_t)row * MLAT + col] = fmaxf(acc[rf][cf][r] + be, 0.f);
                }
            }
    }
}

// ---------------------------------------------------------------------------
// K2: R6/R9 VERBATIM. 2 waves/row, u[8] f32 codes, ballot bisection + exact
// Δ-band np-order fixup, z finalized in place, thread-per-dim decode.
__global__ __launch_bounds__(128, 8) void k_topk_decode(
        float* __restrict__ zbuf, float* __restrict__ xhat,
        const float* __restrict__ WdT, const float* __restrict__ bdec,
        const float* __restrict__ x, const float* __restrict__ Wenc,
        const float* __restrict__ benc) {
    __shared__ float sval[KSEL];
    __shared__ int   sidx[KSEL];
    __shared__ float bval[128];
    __shared__ int   bidx[128];
    __shared__ unsigned char bselm[128];
    __shared__ unsigned scom[4];
    __shared__ int stot[2];

    const int tid  = threadIdx.x;     // 0..127
    const int lane = tid & 63;
    const int w    = tid >> 6;        // wave 0/1: owns elements w*2048 ..
    const size_t row = blockIdx.x;
    float* zr = zbuf + row * MLAT;
    const uint4* zu = (const uint4*)zr + (w << 9);

    // element (half-local): q*256 + lane*4 + c ; global = w*2048 + that
    uint4 u[8];
#pragma unroll
    for (int q = 0; q < 8; ++q) u[q] = zu[(q << 6) + lane];

    // ---- row max (v >= 0 so uint order == float order)
    unsigned mx = 0u;
#pragma unroll
    for (int q = 0; q < 8; ++q)
        mx = max(mx, max(max(u[q].x, u[q].y), max(u[q].z, u[q].w)));
#pragma unroll
    for (int d = 32; d >= 1; d >>= 1) mx = max(mx, (unsigned)__shfl_xor((int)mx, d, 64));
    if (lane == 0) scom[w] = mx;
    __syncthreads();
    mx = max(scom[0], scom[1]);
    __syncthreads();

    // ---- distributed count(v >= T): ballots per wave + LDS combine
#define CNT_GE(T, OUTC)                                              \
    {                                                                \
        int _c = 0;                                                  \
        _Pragma("unroll")                                            \
        for (int q = 0; q < 8; ++q) {                                \
            _c += __popcll(__ballot(u[q].x >= (T)));                 \
            _c += __popcll(__ballot(u[q].y >= (T)));                 \
            _c += __popcll(__ballot(u[q].z >= (T)));                 \
            _c += __popcll(__ballot(u[q].w >= (T)));                 \
        }                                                            \
        if (lane == 0) scom[2 + w] = (unsigned)_c;                   \
        __syncthreads();                                             \
        OUTC = (int)(scom[2] + scom[3]);                             \
        __syncthreads();                                             \
    }

    // ---- bisection for T (seed window, early exit)
    unsigned T;
    {
        unsigned hi = mx + 1u;
        unsigned lo = (mx > 0x01800000u) ? (mx - 0x01800000u) : 0u;
        int c;
        CNT_GE(lo, c);
        if (c < KSEL) { lo = 0u; c = MLAT; }
        if (c == KSEL) {
            T = lo;
        } else {
            for (;;) {
                if (hi - lo <= 1u) { T = lo; break; }
                unsigned mid = lo + ((hi - lo) >> 1);
                int cm;
                CNT_GE(mid, cm);
                if (cm == KSEL) { T = mid; break; }
                if (cm > KSEL) lo = mid; else hi = mid;
            }
        }
    }

    // ---- band classification (identical constants to R5-R11)
    const float tau   = __uint_as_float(T);
    const float DELTA = 2.5e-4f;
    const float PAD   = 5.0e-5f;
    const unsigned DH = __float_as_uint(tau + DELTA + PAD);
    const unsigned DL = __float_as_uint(fmaxf(tau - DELTA, 0.f));

    unsigned inm = 0u, bandm = 0u;   // per-lane 32-bit masks, bit = q*4+c
#pragma unroll
    for (int q = 0; q < 8; ++q) {
        unsigned vv[4] = {u[q].x, u[q].y, u[q].z, u[q].w};
#pragma unroll
        for (int c = 0; c < 4; ++c) {
            unsigned bit = 1u << (4 * q + c);
            if (vv[c] > DH) inm |= bit;
            else if (vv[c] >= DL) bandm |= bit;
        }
    }
    {
        int packed = (__popc(inm) << 16) | __popc(bandm);
#pragma unroll
        for (int d = 32; d >= 1; d >>= 1) packed += __shfl_xor(packed, d, 64);
        if (lane == 0) scom[2 + w] = (unsigned)packed;
        __syncthreads();
    }
    int A   = (int)((scom[2] >> 16) + (scom[3] >> 16));
    int BCt = (int)((scom[2] & 0xFFFFu) + (scom[3] & 0xFFFFu));
    __syncthreads();
    int need = KSEL - A;

    unsigned sel;
    if (need <= 0) {
        sel = inm;
    } else if (BCt == need) {
        sel = inm | bandm;
    } else {
        // ---- exact fixup: recompute band members with np-order f32 chain
        int BC2 = min(BCt, 128);
        int bc = __popc(bandm);
        int pre = bc;
#pragma unroll
        for (int d = 1; d < 64; d <<= 1) {
            int y = __shfl_up(pre, d, 64);
            if (lane >= d) pre += y;
        }
        int wtot = __shfl(pre, 63, 64);
        if (lane == 0) stot[w] = wtot;
        __syncthreads();
        int sbase = (pre - bc) + (w ? stot[0] : 0);
        {
            unsigned mm = bandm; int o = 0;
            while (mm) {
                int bp = __ffs(mm) - 1; mm &= mm - 1;
                int slot = sbase + o; ++o;
                if (slot < 128)
                    bidx[slot] = (w << 11) + ((bp >> 2) << 8) + (lane << 2) + (bp & 3);
            }
        }
        __syncthreads();
        for (int s = tid; s < BC2; s += 128) {
            int j = bidx[s];
            const float* wr = Wenc + (size_t)j * DDIM;
            const float* xr = x + row * DDIM;
            float a = 0.f;
            for (int k = 0; k < DDIM; ++k) a = fmaf(xr[k] - bdec[k], wr[k], a);
            bval[s] = fmaxf(a + benc[j], 0.f);
        }
        __syncthreads();
        if (tid == 0) {
            for (int s = 0; s < BC2; ++s) bselm[s] = 0;
            int take = min(need, BC2);
            for (int it = 0; it < take; ++it) {
                float bv = -1.f; int bi = 0x7FFFFFFF, bs = 0;
                for (int s = 0; s < BC2; ++s) {
                    if (bselm[s]) continue;
                    float v = bval[s]; int j = bidx[s];
                    if (v > bv || (v == bv && j < bi)) { bv = v; bi = j; bs = s; }
                }
                bselm[bs] = 1;
            }
        }
        __syncthreads();
        sel = inm;
        {
            unsigned mm = bandm; int o = 0;
            while (mm) {
                int bp = __ffs(mm) - 1; mm &= mm - 1;
                int slot = sbase + o; ++o;
                if (slot < 128 && bselm[slot]) sel |= 1u << bp;
            }
        }
        __syncthreads();
    }

    // ---- compaction position across both waves
    int scnt = __popc(sel);
    int pre = scnt;
#pragma unroll
    for (int d = 1; d < 64; d <<= 1) {
        int y = __shfl_up(pre, d, 64);
        if (lane >= d) pre += y;
    }
    int wtot2 = __shfl(pre, 63, 64);
    if (lane == 0) stot[w] = wtot2;
    __syncthreads();
    int pos = pre - scnt + (w ? stot[0] : 0);
    int total = stot[0] + stot[1];

    // ---- finalize z (own half) + compact (v, idx) to LDS
    uint4* zw = (uint4*)zr + (w << 9);
#pragma unroll
    for (int q = 0; q < 8; ++q) {
        uint4 o;
        bool s0 = (sel >> (4 * q + 0)) & 1u;
        bool s1 = (sel >> (4 * q + 1)) & 1u;
        bool s2 = (sel >> (4 * q + 2)) & 1u;
        bool s3 = (sel >> (4 * q + 3)) & 1u;
        o.x = s0 ? u[q].x : 0u;
        o.y = s1 ? u[q].y : 0u;
        o.z = s2 ? u[q].z : 0u;
        o.w = s3 ? u[q].w : 0u;
        int base = (w << 11) + (q << 8) + (lane << 2);
        if (s0 && pos < KSEL) { sval[pos] = __uint_as_float(u[q].x); sidx[pos] = base + 0; ++pos; }
        if (s1 && pos < KSEL) { sval[pos] = __uint_as_float(u[q].y); sidx[pos] = base + 1; ++pos; }
        if (s2 && pos < KSEL) { sval[pos] = __uint_as_float(u[q].z); sidx[pos] = base + 2; ++pos; }
        if (s3 && pos < KSEL) { sval[pos] = __uint_as_float(u[q].w); sidx[pos] = base + 3; ++pos; }
        zw[(q << 6) + lane] = o;
    }
    __syncthreads();

    // ---- decode: thread tid owns output dim d = tid (WdT stays L2-cached)
    float a = bdec[tid];
    int tt = min(total, KSEL);
#pragma unroll 4
    for (int s = 0; s < tt; ++s) {
        float v = sval[s];
        int   j = sidx[s];
        a = fmaf(v, WdT[(size_t)j * DDIM + tid], a);
    }
    xhat[row * DDIM + tid] = a;
}

// ---------------------------------------------------------------------------
extern "C" void kernel_launch(void* const* d_in, const int* in_sizes, int n_in,
                              void* d_out, int out_size, void* d_ws, size_t ws_size,
                              hipStream_t stream) {
    const float* x    = (const float*)d_in[0];
    const float* Wenc = (const float*)d_in[1];
    const float* benc = (const float*)d_in[2];
    const float* Wdec = (const float*)d_in[3];
    const float* bdec = (const float*)d_in[4];

    const int N = in_sizes[0] / DDIM;               // 65536
    float* xhat = (float*)d_out;                    // [N][128] f32 (final)
    float* zbuf = (float*)d_out + (size_t)N * DDIM; // [N][4096] (z~, finalized in place)

    // x splits live in the xhat region until decode (exact fit)
    ushort* xhi = (ushort*)d_out;
    ushort* xlo = xhi + (size_t)N * DDIM;

    // workspace: whiP | wloP | WdT  (1 MB + 1 MB + 2 MB)
    ushort* whiP = (ushort*)d_ws;
    ushort* wloP = whiP + (size_t)MLAT * DDIM;
    float*  WdT  = (float*)((char*)d_ws + 2u * 1024u * 1024u);

    k_split_x<<<dim3((N * DDIM) / 1024), dim3(256), 0, stream>>>(x, bdec, xhi, xlo);
    k_prep<<<dim3(512 + 2048), dim3(256), 0, stream>>>(Wenc, whiP, wloP, Wdec, WdT);
    k_encode_mfma<<<dim3(N / 128), dim3(256), 0, stream>>>(xhi, xlo, whiP, wloP, benc, zbuf);
    k_topk_decode<<<dim3(N), dim3(128), 0, stream>>>(zbuf, xhat, WdT, bdec, x, Wenc, benc);
}